// Round 10
// baseline (214.557 us; speedup 1.0000x reference)
//
#include <hip/hip_runtime.h>
#include <math.h>

#define N 4096
#define P 128
#define LDIM 32
#define CHA 16   // alpha chunks: 2 i-tiles each, grid 1024 = 4 blocks/CU
#define CHB 12   // betaez chunks: ragged 3/2 i-tiles, grid 768 = 3 blocks/CU

typedef unsigned int u32;
typedef unsigned short u16;
typedef short s16x8 __attribute__((ext_vector_type(8)));
typedef float f32x4 __attribute__((ext_vector_type(4)));

// ---------- bf16 helpers (RNE) ----------
__device__ __forceinline__ u16 f2b(float f) {
  u32 u = __float_as_uint(f);
  u += 0x7fffu + ((u >> 16) & 1u);
  return (u16)(u >> 16);
}
__device__ __forceinline__ float b2f(u16 h) { return __uint_as_float(((u32)h) << 16); }

__device__ __forceinline__ float geluf(float a) {
  return 0.5f * a * (1.0f + erff(a * 0.70710678118654752f));
}

#define MFMA(a, b, c) __builtin_amdgcn_mfma_f32_16x16x32_bf16((a), (b), (c), 0, 0, 0)

// ---------- K0: zero mdb + ezflag + out ----------
__global__ __launch_bounds__(256) void k_init(u32* __restrict__ mdb, u32* __restrict__ ezflag,
                                              float* __restrict__ out) {
  for (int i = threadIdx.x; i < CHB * 64; i += 256) ezflag[i] = 0u;
  if (threadIdx.x == 0) { *mdb = 0u; out[0] = 0.0f; }
}

// ---------- K1: xb = bf16(x), xbT = transpose, x2 full-row ----------
__global__ __launch_bounds__(256) void k_prep(const float* __restrict__ x, u16* __restrict__ xb,
                                              u16* __restrict__ xbT, float* __restrict__ x2) {
  __shared__ u16 tlT[128][40];
  const int bi = blockIdx.x * 32;
  const int tid = threadIdx.x;
  const int r = tid >> 3, cg = (tid & 7) * 16;
  const float* src = &x[(size_t)(bi + r) * P + cg];
  float4 v0 = *(const float4*)(src + 0);
  float4 v1 = *(const float4*)(src + 4);
  float4 v2 = *(const float4*)(src + 8);
  float4 v3 = *(const float4*)(src + 12);
  u16 h[16];
  h[0] = f2b(v0.x); h[1] = f2b(v0.y); h[2] = f2b(v0.z); h[3] = f2b(v0.w);
  h[4] = f2b(v1.x); h[5] = f2b(v1.y); h[6] = f2b(v1.z); h[7] = f2b(v1.w);
  h[8] = f2b(v2.x); h[9] = f2b(v2.y); h[10] = f2b(v2.z); h[11] = f2b(v2.w);
  h[12] = f2b(v3.x); h[13] = f2b(v3.y); h[14] = f2b(v3.z); h[15] = f2b(v3.w);
  float s = 0.0f;
#pragma unroll
  for (int e = 0; e < 16; e++) { float f = b2f(h[e]); s = fmaf(f, f, s); }
  s += __shfl_down(s, 4); s += __shfl_down(s, 2); s += __shfl_down(s, 1);
  if ((tid & 7) == 0) x2[bi + r] = s;
  uint4 p0, p1;
  p0.x = (u32)h[0] | ((u32)h[1] << 16);  p0.y = (u32)h[2] | ((u32)h[3] << 16);
  p0.z = (u32)h[4] | ((u32)h[5] << 16);  p0.w = (u32)h[6] | ((u32)h[7] << 16);
  p1.x = (u32)h[8] | ((u32)h[9] << 16);  p1.y = (u32)h[10] | ((u32)h[11] << 16);
  p1.z = (u32)h[12] | ((u32)h[13] << 16); p1.w = (u32)h[14] | ((u32)h[15] << 16);
  *(uint4*)&xb[(size_t)(bi + r) * P + cg] = p0;
  *(uint4*)&xb[(size_t)(bi + r) * P + cg + 8] = p1;
#pragma unroll
  for (int e = 0; e < 16; e++) tlT[cg + e][r] = h[e];
  __syncthreads();
  const int c = tid >> 1, hh = tid & 1;
  uint4 q0 = *(const uint4*)&tlT[c][hh * 16];
  uint4 q1 = *(const uint4*)&tlT[c][hh * 16 + 8];
  *(uint4*)&xbT[(size_t)c * N + bi + hh * 16] = q0;
  *(uint4*)&xbT[(size_t)c * N + bi + hh * 16 + 8] = q1;
}

// ---------- K1b: anchor lower bound on max d2 ----------
__global__ __launch_bounds__(128) void k_anchor(const u16* __restrict__ xb, const float* __restrict__ x2,
                                                u32* __restrict__ mdb) {
  const int i = blockIdx.x * 128 + threadIdx.x;
  const uint4* ra = (const uint4*)(xb + (size_t)i * P);
  const uint4* r0 = (const uint4*)xb;
  float dot = 0.0f;
#pragma unroll
  for (int q = 0; q < 16; ++q) {
    uint4 a = ra[q], b = r0[q];
    u32 aa[4] = {a.x, a.y, a.z, a.w}, bb[4] = {b.x, b.y, b.z, b.w};
#pragma unroll
    for (int e = 0; e < 4; e++) {
      dot = fmaf(b2f((u16)(aa[e] & 0xffffu)), b2f((u16)(bb[e] & 0xffffu)), dot);
      dot = fmaf(b2f((u16)(aa[e] >> 16)), b2f((u16)(bb[e] >> 16)), dot);
    }
  }
  float d2 = fmaxf(x2[i] + x2[0] - 2.0f * dot, 0.0f);
#pragma unroll
  for (int o = 32; o > 0; o >>= 1) d2 = fmaxf(d2, __shfl_down(d2, o));
  if ((threadIdx.x & 63) == 0) atomicMax(mdb, __float_as_uint(d2));
}

// ---------- K2: full max pairwise d2 — early-outs if anchor proves md >= max(r) ----------
__global__ __launch_bounds__(512, 4) void k_grammax(const u16* __restrict__ xb, const float* __restrict__ x2,
                                                    u32* __restrict__ mdb,
                                                    const float* __restrict__ r0p, const float* __restrict__ r1p,
                                                    const float* __restrict__ r2p) {
  const float rmax = fmaxf(r0p[0], fmaxf(r1p[0], r2p[0])) * 1.02f;
  if (__uint_as_float(*mdb) >= rmax * rmax) return;
  __shared__ uint4 LA[1024];
  const int j0 = blockIdx.x * 64;
  const int cid = blockIdx.y;
  if (cid * 512 + 512 <= j0) return;
  const int tid = threadIdx.x;
  const int lane = tid & 63, w = tid >> 6;
  const int lm = lane & 15, quad = lane >> 4;
  {
    const uint4* g = (const uint4*)(xb + (size_t)j0 * P);
#pragma unroll
    for (int it = 0; it < 2; ++it) {
      int c = it * 512 + tid;
      int row = c >> 4, ch = c & 15;
      LA[row * 16 + (ch ^ (row & 7))] = g[c];
    }
  }
  float x2j[4][4];
#pragma unroll
  for (int u = 0; u < 4; u++)
#pragma unroll
    for (int reg = 0; reg < 4; reg++) x2j[u][reg] = x2[j0 + u * 16 + quad * 4 + reg];
  __syncthreads();
  float lmax = 0.0f;
  for (int t = 0; t < 4; ++t) {
    const int i0 = cid * 512 + t * 128;
    if (i0 + 128 <= j0) continue;
    f32x4 accG[4];
#pragma unroll
    for (int u = 0; u < 4; u++) accG[u] = {0.f, 0.f, 0.f, 0.f};
    const u16* gb = xb + (size_t)(i0 + w * 16 + lm) * P;
#pragma unroll
    for (int ks = 0; ks < 4; ++ks) {
      s16x8 bf = *(const s16x8*)(gb + ks * 32 + quad * 8);
      s16x8 af[4];
#pragma unroll
      for (int u = 0; u < 4; u++) { int m = u * 16 + lm; af[u] = *(const s16x8*)&LA[m * 16 + ((ks * 4 + quad) ^ (m & 7))]; }
#pragma unroll
      for (int u = 0; u < 4; u++) accG[u] = MFMA(af[u], bf, accG[u]);
    }
    float x2i = x2[i0 + w * 16 + lm];
#pragma unroll
    for (int u = 0; u < 4; u++)
#pragma unroll
      for (int reg = 0; reg < 4; reg++) lmax = fmaxf(lmax, x2j[u][reg] + x2i - 2.0f * accG[u][reg]);
  }
#pragma unroll
  for (int o = 32; o > 0; o >>= 1) lmax = fmaxf(lmax, __shfl_down(lmax, o));
  if (lane == 0) atomicMax(mdb, __float_as_uint(lmax));
}

// ---------- K3: fused alpha, 2 i-tiles/chunk, 4 blocks/CU ----------
__global__ __launch_bounds__(512, 8) void k_alpha(const u16* __restrict__ xb, const u16* __restrict__ xbT,
                                                  const float* __restrict__ x2,
                                                  float* __restrict__ muP, float* __restrict__ S1P,
                                                  const float* __restrict__ r0p, const u32* __restrict__ mdb) {
  __shared__ uint4 LA[1024];     // xb_j 64x128 swizzled
  __shared__ u16 W16[64 * 136];  // W[j][i]
  __shared__ float S1L[64];
  const int j0 = blockIdx.x * 64, cid = blockIdx.y;
  const int tid = threadIdx.x;
  const int lane = tid & 63, w = tid >> 6;
  const int lm = lane & 15, quad = lane >> 4;
  {
    const uint4* g = (const uint4*)(xb + (size_t)j0 * P);
#pragma unroll
    for (int it = 0; it < 2; ++it) {
      int c = it * 512 + tid;
      int row = c >> 4, ch = c & 15;
      LA[row * 16 + (ch ^ (row & 7))] = g[c];
    }
  }
  if (tid < 64) S1L[tid] = 0.0f;
  const float mdf = sqrtf(fmaxf(__uint_as_float(*mdb), 1e-12f));
  const float re = fminf(r0p[0], mdf);
  const float re2 = re * re, inv_re2 = 1.0f / re2;
  float x2j[4];
#pragma unroll
  for (int v = 0; v < 4; v++) x2j[v] = x2[j0 + v * 16 + lm];
  f32x4 accPV[4];
#pragma unroll
  for (int u = 0; u < 4; u++) accPV[u] = {0.f, 0.f, 0.f, 0.f};
  float sjv[4] = {0.f, 0.f, 0.f, 0.f};
  __syncthreads();
#pragma unroll
  for (int t = 0; t < 2; ++t) {
    const int i0 = (cid * 2 + t) * 128;
    f32x4 accG[4];
#pragma unroll
    for (int v = 0; v < 4; v++) accG[v] = {0.f, 0.f, 0.f, 0.f};
    const u16* ga = xb + (size_t)(i0 + w * 16 + lm) * P;
#pragma unroll
    for (int ks = 0; ks < 4; ++ks) {
      s16x8 af = *(const s16x8*)(ga + ks * 32 + quad * 8);
      s16x8 bf[4];
#pragma unroll
      for (int v = 0; v < 4; v++) { int m = v * 16 + lm; bf[v] = *(const s16x8*)&LA[m * 16 + ((ks * 4 + quad) ^ (m & 7))]; }
#pragma unroll
      for (int v = 0; v < 4; v++) accG[v] = MFMA(af, bf[v], accG[v]);
    }
    float4 x2iv = *(const float4*)&x2[i0 + w * 16 + quad * 4];
    const float xi[4] = {x2iv.x, x2iv.y, x2iv.z, x2iv.w};
    u16 wv4[4][4];
#pragma unroll
    for (int v = 0; v < 4; v++)
#pragma unroll
      for (int reg = 0; reg < 4; reg++) {
        float d2 = fmaxf(xi[reg] + x2j[v] - 2.0f * accG[v][reg], 1e-12f);
        float wt = 0.0f;
        if (d2 < re2) { float b = 1.0f - d2 * inv_re2; wt = b * b * b; }
        sjv[v] += wt;
        wv4[v][reg] = f2b(wt);
      }
    __syncthreads();  // prev tile's W16 readers done
#pragma unroll
    for (int v = 0; v < 4; v++) {
      ushort4 pk; pk.x = wv4[v][0]; pk.y = wv4[v][1]; pk.z = wv4[v][2]; pk.w = wv4[v][3];
      *(ushort4*)&W16[(v * 16 + lm) * 136 + w * 16 + quad * 4] = pk;
    }
    __syncthreads();
    const u16* gx = xbT + (size_t)(w * 16 + lm) * N + i0;
#pragma unroll
    for (int ks = 0; ks < 4; ++ks) {
      s16x8 bx = *(const s16x8*)(gx + ks * 32 + quad * 8);
      s16x8 aw[4];
#pragma unroll
      for (int u = 0; u < 4; u++) { int m = u * 16 + lm; aw[u] = *(const s16x8*)&W16[m * 136 + ks * 32 + quad * 8]; }
#pragma unroll
      for (int u = 0; u < 4; u++) accPV[u] = MFMA(aw[u], bx, accPV[u]);
    }
  }
  float* mu = muP + (size_t)cid * N * P;
#pragma unroll
  for (int u = 0; u < 4; u++)
#pragma unroll
    for (int reg = 0; reg < 4; reg++)
      __builtin_nontemporal_store(accPV[u][reg],
        &mu[(size_t)(j0 + u * 16 + quad * 4 + reg) * P + w * 16 + lm]);
#pragma unroll
  for (int v = 0; v < 4; v++) atomicAdd(&S1L[v * 16 + lm], sjv[v]);
  __syncthreads();
  if (tid < 64) S1P[cid * N + j0 + tid] = S1L[tid];
}

// ---------- K4: U finalize, Ub=bf16(U), u2,cj from bf16 ----------
__global__ __launch_bounds__(128) void k_finU(const float* __restrict__ x, const u16* __restrict__ xb,
                                              const float* __restrict__ muP, const float* __restrict__ S1P,
                                              u16* __restrict__ Ub, float* __restrict__ u2, float* __restrict__ cj) {
  const int j = blockIdx.x, t = threadIdx.x;
  float ssum = 0.0f, msum = 0.0f;
#pragma unroll
  for (int c = 0; c < CHA; ++c) {
    ssum += S1P[c * N + j];
    msum += __builtin_nontemporal_load(&muP[((size_t)c * N + j) * P + t]);
  }
  float xv = x[(size_t)j * P + t];
  float uval = 0.0f;
  if (ssum > 0.0f) uval = xv - msum / ssum;
  u16 ub = f2b(uval);
  Ub[(size_t)j * P + t] = ub;
  float uf = b2f(ub);
  float xbf = b2f(xb[(size_t)j * P + t]);
  float a = uf * uf, b = xbf * uf;
#pragma unroll
  for (int o = 32; o > 0; o >>= 1) { a += __shfl_down(a, o); b += __shfl_down(b, o); }
  __shared__ float ra[2], rb[2];
  if ((t & 63) == 0) { ra[t >> 6] = a; rb[t >> 6] = b; }
  __syncthreads();
  if (t == 0) { u2[j] = ra[0] + ra[1]; cj[j] = rb[0] + rb[1]; }
}

// ---------- K5: fused beta; exact all-zero-tile skip of W-write/PV; flagged ez partials ----------
__global__ __launch_bounds__(512, 6) void k_betaez(const u16* __restrict__ xb, const u16* __restrict__ Ub,
                                                   const u16* __restrict__ xbT,
                                                   const float* __restrict__ x2, const float* __restrict__ u2,
                                                   const float* __restrict__ cj,
                                                   float* __restrict__ ezP, float* __restrict__ S2P,
                                                   u32* __restrict__ ezflag,
                                                   const float* __restrict__ r1p, const float* __restrict__ r2p,
                                                   const u32* __restrict__ mdb) {
  __shared__ uint4 LA[1024];
  __shared__ uint4 LU[1024];
  __shared__ u16 W16[64 * 136];
  __shared__ float S2L[64];
  __shared__ u32 Wfl[8];
  const int j0 = blockIdx.x * 64, cid = blockIdx.y;
  const int tid = threadIdx.x;
  const int lane = tid & 63, w = tid >> 6;
  const int lm = lane & 15, quad = lane >> 4;
  {
    const uint4* ga = (const uint4*)(xb + (size_t)j0 * P);
    const uint4* gu = (const uint4*)(Ub + (size_t)j0 * P);
#pragma unroll
    for (int it = 0; it < 2; ++it) {
      int c = it * 512 + tid;
      int row = c >> 4, ch = c & 15;
      int sw = row * 16 + (ch ^ (row & 7));
      LA[sw] = ga[c];
      LU[sw] = gu[c];
    }
  }
  if (tid < 64) S2L[tid] = 0.0f;
  const float mdf = sqrtf(fmaxf(__uint_as_float(*mdb), 1e-12f));
  const float r1e = fminf(r1p[0], mdf), r2e = fminf(r2p[0], mdf);
  const float r1q = r1e * r1e, r1h = 0.25f * r1q;
  const float r2q = r2e * r2e, r2h = 0.25f * r2q;
  const float inv_r1 = 1.0f / r1e, inv_r2 = 1.0f / r2e;
  float x2j[4], u2j[4], ncj[4];
#pragma unroll
  for (int v = 0; v < 4; v++) {
    int jj = j0 + v * 16 + lm;
    x2j[v] = x2[jj]; u2j[v] = u2[jj]; ncj[v] = -cj[jj];
  }
  f32x4 accPV[4];
#pragma unroll
  for (int u = 0; u < 4; u++) accPV[u] = {0.f, 0.f, 0.f, 0.f};
  float sjv[4] = {0.f, 0.f, 0.f, 0.f};
  bool blockAny = false;
  // ragged chunking: chunks 0..7 -> 3 i-tiles, 8..11 -> 2
  const int tstart = (cid < 8) ? cid * 3 : 24 + (cid - 8) * 2;
  const int tcnt = (cid < 8) ? 3 : 2;
  __syncthreads();
  for (int t = 0; t < tcnt; ++t) {
    const int i0 = (tstart + t) * 128;
    f32x4 accG[4], accP[4];
#pragma unroll
    for (int v = 0; v < 4; v++) {
      accG[v] = {0.f, 0.f, 0.f, 0.f};
      accP[v] = {ncj[v], ncj[v], ncj[v], ncj[v]};  // ps = x_i.U_j - cj_j via C-init
    }
    const u16* ga = xb + (size_t)(i0 + w * 16 + lm) * P;
#pragma unroll
    for (int ks = 0; ks < 4; ++ks) {
      s16x8 af = *(const s16x8*)(ga + ks * 32 + quad * 8);
      s16x8 bf[4], bu[4];
#pragma unroll
      for (int v = 0; v < 4; v++) {
        int m = v * 16 + lm;
        int off = m * 16 + ((ks * 4 + quad) ^ (m & 7));
        bf[v] = *(const s16x8*)&LA[off];
        bu[v] = *(const s16x8*)&LU[off];
      }
#pragma unroll
      for (int v = 0; v < 4; v++) {
        accG[v] = MFMA(af, bf[v], accG[v]);
        accP[v] = MFMA(af, bu[v], accP[v]);
      }
    }
    float4 x2iv = *(const float4*)&x2[i0 + w * 16 + quad * 4];
    const float xi[4] = {x2iv.x, x2iv.y, x2iv.z, x2iv.w};
    u16 wv4[4][4];
    u32 nz = 0u;
#pragma unroll
    for (int v = 0; v < 4; v++)
#pragma unroll
      for (int reg = 0; reg < 4; reg++) {
        float d2 = fmaxf(xi[reg] + x2j[v] - 2.0f * accG[v][reg], 1e-12f);
        float ps = accP[v][reg];
        float du2 = fmaxf(ps * ps * u2j[v], 1e-6f);
        float dv2 = fmaxf(d2 - du2, 1e-6f);
        float wt;
        if (dv2 >= r1q || du2 >= r2q) {
          wt = 0.0f;
        } else if (dv2 < r1h && du2 < r2h) {
          wt = 1.0f;
        } else {
          float wa = 1.0f;
          if (dv2 >= r1h) { float dv = sqrtf(dv2); float tt = 2.0f * dv * inv_r1 - 1.0f; float b = 1.0f - tt * tt; wa = b * b * b; }
          float wb = 1.0f;
          if (du2 >= r2h) { float du = sqrtf(du2); float tt = 2.0f * du * inv_r2 - 1.0f; float b = 1.0f - tt * tt; wb = b * b * b; }
          wt = wa * wb;
        }
        sjv[v] += wt;
        u16 hv = f2b(wt);
        wv4[v][reg] = hv;
        nz |= hv;
      }
    if (lane == 0) Wfl[w] = 0u;
    // wave-any of nonzero W element
    bool wany = __any(nz != 0u);
    if (lane == 0 && wany) Wfl[w] = 1u;
    __syncthreads();
    u32 tileAny = Wfl[0] | Wfl[1] | Wfl[2] | Wfl[3] | Wfl[4] | Wfl[5] | Wfl[6] | Wfl[7];
    if (tileAny) {  // uniform across block
      blockAny = true;
#pragma unroll
      for (int v = 0; v < 4; v++) {
        ushort4 pk; pk.x = wv4[v][0]; pk.y = wv4[v][1]; pk.z = wv4[v][2]; pk.w = wv4[v][3];
        *(ushort4*)&W16[(v * 16 + lm) * 136 + w * 16 + quad * 4] = pk;
      }
      __syncthreads();
      const u16* gx = xbT + (size_t)(w * 16 + lm) * N + i0;
#pragma unroll
      for (int ks = 0; ks < 4; ++ks) {
        s16x8 bx = *(const s16x8*)(gx + ks * 32 + quad * 8);
        s16x8 aw[4];
#pragma unroll
        for (int u = 0; u < 4; u++) { int m = u * 16 + lm; aw[u] = *(const s16x8*)&W16[m * 136 + ks * 32 + quad * 8]; }
#pragma unroll
        for (int u = 0; u < 4; u++) accPV[u] = MFMA(aw[u], bx, accPV[u]);
      }
    }
  }
  if (blockAny) {
    float* ez = ezP + (size_t)cid * N * P;
#pragma unroll
    for (int u = 0; u < 4; u++)
#pragma unroll
      for (int reg = 0; reg < 4; reg++)
        __builtin_nontemporal_store(accPV[u][reg],
          &ez[(size_t)(j0 + u * 16 + quad * 4 + reg) * P + w * 16 + lm]);
    if (tid == 0) ezflag[cid * 64 + blockIdx.x] = 1u;
  }
#pragma unroll
  for (int v = 0; v < 4; v++) atomicAdd(&S2L[v * 16 + lm], sjv[v]);
  __syncthreads();
  if (tid < 64) S2P[cid * N + j0 + tid] = S2L[tid];
}

// ---------- K6: e_Z reduce (flag-gated) + autoencoder + MSE ----------
#define AE_ROWS 16
__global__ __launch_bounds__(256) void k_ae(const float* __restrict__ x, const float* __restrict__ ezP,
                                            const float* __restrict__ S2P, const u32* __restrict__ ezflag,
                                            const float* __restrict__ We1, const float* __restrict__ be1,
                                            const float* __restrict__ We2, const float* __restrict__ be2,
                                            const float* __restrict__ Wd1, const float* __restrict__ bd1,
                                            const float* __restrict__ Wd2, const float* __restrict__ bd2,
                                            float* __restrict__ out) {
  __shared__ float We1T[P][33];
  __shared__ float We2T[LDIM][33];
  __shared__ float Wd1T[LDIM][33];
  __shared__ float Wd2T[LDIM][129];
  __shared__ float ezs[AE_ROWS][P];
  __shared__ float h1s[AE_ROWS][LDIM], zbs[AE_ROWS][LDIM], h2s[AE_ROWS][LDIM];
  __shared__ float be1s[LDIM], be2s[LDIM], bd1s[LDIM], bd2s[P];
  __shared__ float s2s[AE_ROWS];
  __shared__ u32 efl[CHB];
  const int tid = threadIdx.x;
  const int r0 = blockIdx.x * AE_ROWS;
  const int jt = r0 >> 6;  // 64-row tile index
  for (int idx = tid; idx < P * LDIM; idx += 256) {
    int o = idx >> 7, k = idx & 127;
    We1T[k][o] = We1[idx];
    int o2 = idx >> 5, k2 = idx & 31;
    Wd2T[k2][o2] = Wd2[idx];
  }
  for (int idx = tid; idx < LDIM * LDIM; idx += 256) {
    int o = idx >> 5, k = idx & 31;
    We2T[k][o] = We2[idx];
    Wd1T[k][o] = Wd1[idx];
  }
  if (tid < LDIM) { be1s[tid] = be1[tid]; be2s[tid] = be2[tid]; bd1s[tid] = bd1[tid]; }
  if (tid < P) bd2s[tid] = bd2[tid];
  if (tid < CHB) efl[tid] = ezflag[tid * 64 + jt];
  if (tid >= 128 && tid < 128 + AE_ROWS) {
    int r = tid - 128;
    float s = 0.0f;
#pragma unroll
    for (int c = 0; c < CHB; ++c) s += S2P[c * N + r0 + r];
    s2s[r] = s;
  }
  __syncthreads();
  for (int idx = tid; idx < AE_ROWS * P; idx += 256) {
    int r = idx >> 7, col = idx & 127;
    int row = r0 + r;
    float es = 0.0f;
#pragma unroll
    for (int c = 0; c < CHB; ++c)
      if (efl[c]) es += __builtin_nontemporal_load(&ezP[((size_t)c * N + row) * P + col]);
    float xv = x[(size_t)row * P + col];
    ezs[r][col] = (s2s[r] > 0.0f) ? (es / s2s[r]) : xv;
  }
  __syncthreads();
  {
    const int o = tid & 31, rh = tid >> 5;
#pragma unroll
    for (int rr = 0; rr < 2; rr++) {
      int r = rh + rr * 8;
      float a = be1s[o];
#pragma unroll 8
      for (int k = 0; k < P; k++) a = fmaf(We1T[k][o], ezs[r][k], a);
      h1s[r][o] = geluf(a);
    }
  }
  __syncthreads();
  {
    const int o = tid & 31, rh = tid >> 5;
#pragma unroll
    for (int rr = 0; rr < 2; rr++) {
      int r = rh + rr * 8;
      float a = be2s[o];
#pragma unroll
      for (int k = 0; k < LDIM; k++) a = fmaf(We2T[k][o], h1s[r][k], a);
      zbs[r][o] = a;
    }
  }
  __syncthreads();
  {
    const int o = tid & 31, rh = tid >> 5;
#pragma unroll
    for (int rr = 0; rr < 2; rr++) {
      int r = rh + rr * 8;
      float a = bd1s[o];
#pragma unroll
      for (int k = 0; k < LDIM; k++) a = fmaf(Wd1T[k][o], zbs[r][k], a);
      h2s[r][o] = geluf(a);
    }
  }
  __syncthreads();
  {
    const int o = tid & 127, rh = tid >> 7;
    float part = 0.0f;
#pragma unroll
    for (int rr = 0; rr < 8; rr++) {
      int r = rh + rr * 2;
      int row = r0 + r;
      float a = bd2s[o];
#pragma unroll
      for (int k = 0; k < LDIM; k++) a = fmaf(Wd2T[k][o], h2s[r][k], a);
      float xh = 1.0f / (1.0f + expf(-a));
      float diff = x[(size_t)row * P + o] - xh;
      part = fmaf(diff, diff, part);
    }
#pragma unroll
    for (int off = 32; off > 0; off >>= 1) part += __shfl_down(part, off);
    if ((tid & 63) == 0) atomicAdd(out, part * (1.0f / ((float)N * (float)P)));
  }
}

extern "C" void kernel_launch(void* const* d_in, const int* in_sizes, int n_in,
                              void* d_out, int out_size, void* d_ws, size_t ws_size,
                              hipStream_t stream) {
  const float* x   = (const float*)d_in[0];
  const float* r0  = (const float*)d_in[1];
  const float* r1  = (const float*)d_in[2];
  const float* r2  = (const float*)d_in[3];
  const float* We1 = (const float*)d_in[4];
  const float* be1 = (const float*)d_in[5];
  const float* We2 = (const float*)d_in[6];
  const float* be2 = (const float*)d_in[7];
  const float* Wd1 = (const float*)d_in[8];
  const float* bd1 = (const float*)d_in[9];
  const float* Wd2 = (const float*)d_in[10];
  const float* bd2 = (const float*)d_in[11];
  float* out = (float*)d_out;

  char* base = (char*)d_ws;
  size_t off = 0;
  u16* xb  = (u16*)(base + off); off += (size_t)N * P * 2;
  u16* xbT = (u16*)(base + off); off += (size_t)N * P * 2;
  u16* Ub  = (u16*)(base + off); off += (size_t)N * P * 2;
  float* muP = (float*)(base + off); off += (size_t)CHA * N * P * 4;  // 32MB
  float* ezP = (float*)(base + off); off += (size_t)CHB * N * P * 4;  // 24MB
  float* S1P = (float*)(base + off); off += (size_t)CHA * N * 4;
  float* S2P = (float*)(base + off); off += (size_t)CHB * N * 4;
  float* x2  = (float*)(base + off); off += (size_t)N * 4;
  u32* mdb   = (u32*)(base + off); off += 4;
  u32* ezflag = (u32*)(base + off); off += (size_t)CHB * 64 * 4;
  float* u2  = (float*)(base + off); off += (size_t)N * 4;
  float* cjv = (float*)(base + off); off += (size_t)N * 4;

  hipLaunchKernelGGL(k_init, dim3(1), dim3(256), 0, stream, mdb, ezflag, out);
  hipLaunchKernelGGL(k_prep, dim3(N / 32), dim3(256), 0, stream, x, xb, xbT, x2);
  hipLaunchKernelGGL(k_anchor, dim3(N / 128), dim3(128), 0, stream, xb, x2, mdb);
  hipLaunchKernelGGL(k_grammax, dim3(N / 64, 8), dim3(512), 0, stream, xb, x2, mdb, r0, r1, r2);
  hipLaunchKernelGGL(k_alpha, dim3(N / 64, CHA), dim3(512), 0, stream, xb, xbT, x2, muP, S1P, r0, mdb);
  hipLaunchKernelGGL(k_finU, dim3(N), dim3(128), 0, stream, x, xb, muP, S1P, Ub, u2, cjv);
  hipLaunchKernelGGL(k_betaez, dim3(N / 64, CHB), dim3(512), 0, stream, xb, Ub, xbT, x2, u2, cjv, ezP, S2P, ezflag, r1, r2, mdb);
  hipLaunchKernelGGL(k_ae, dim3(N / AE_ROWS), dim3(256), 0, stream, x, ezP, S2P, ezflag, We1, be1, We2, be2, Wd1, bd1, Wd2, bd2, out);
}

// Round 11
// 174.022 us; speedup vs baseline: 1.2329x; 1.2329x over previous
//
#include <hip/hip_runtime.h>
#include <math.h>

#define N 4096
#define P 128
#define LDIM 32
#define CHUNKS 8
#define ITILES 4

typedef unsigned int u32;
typedef unsigned short u16;
typedef short s16x8 __attribute__((ext_vector_type(8)));
typedef float f32x4 __attribute__((ext_vector_type(4)));

// ---------- bf16 helpers (RNE) ----------
__device__ __forceinline__ u16 f2b(float f) {
  u32 u = __float_as_uint(f);
  u += 0x7fffu + ((u >> 16) & 1u);
  return (u16)(u >> 16);
}
__device__ __forceinline__ float b2f(u16 h) { return __uint_as_float(((u32)h) << 16); }

__device__ __forceinline__ float geluf(float a) {
  return 0.5f * a * (1.0f + erff(a * 0.70710678118654752f));
}

#define MFMA(a, b, c) __builtin_amdgcn_mfma_f32_16x16x32_bf16((a), (b), (c), 0, 0, 0)

// ---------- K1: xb = bf16(x), xbT = transpose, x2 full-row; block0 zeroes mdb/out ----------
__global__ __launch_bounds__(256) void k_prep(const float* __restrict__ x, u16* __restrict__ xb,
                                              u16* __restrict__ xbT, float* __restrict__ x2,
                                              u32* __restrict__ mdb, float* __restrict__ out) {
  __shared__ u16 tlT[128][40];
  const int bi = blockIdx.x * 32;
  const int tid = threadIdx.x;
  if (blockIdx.x == 0 && tid == 0) { *mdb = 0u; out[0] = 0.0f; }
  const int r = tid >> 3, cg = (tid & 7) * 16;
  const float* src = &x[(size_t)(bi + r) * P + cg];
  float4 v0 = *(const float4*)(src + 0);
  float4 v1 = *(const float4*)(src + 4);
  float4 v2 = *(const float4*)(src + 8);
  float4 v3 = *(const float4*)(src + 12);
  u16 h[16];
  h[0] = f2b(v0.x); h[1] = f2b(v0.y); h[2] = f2b(v0.z); h[3] = f2b(v0.w);
  h[4] = f2b(v1.x); h[5] = f2b(v1.y); h[6] = f2b(v1.z); h[7] = f2b(v1.w);
  h[8] = f2b(v2.x); h[9] = f2b(v2.y); h[10] = f2b(v2.z); h[11] = f2b(v2.w);
  h[12] = f2b(v3.x); h[13] = f2b(v3.y); h[14] = f2b(v3.z); h[15] = f2b(v3.w);
  float s = 0.0f;
#pragma unroll
  for (int e = 0; e < 16; e++) { float f = b2f(h[e]); s = fmaf(f, f, s); }
  s += __shfl_down(s, 4); s += __shfl_down(s, 2); s += __shfl_down(s, 1);
  if ((tid & 7) == 0) x2[bi + r] = s;
  uint4 p0, p1;
  p0.x = (u32)h[0] | ((u32)h[1] << 16);  p0.y = (u32)h[2] | ((u32)h[3] << 16);
  p0.z = (u32)h[4] | ((u32)h[5] << 16);  p0.w = (u32)h[6] | ((u32)h[7] << 16);
  p1.x = (u32)h[8] | ((u32)h[9] << 16);  p1.y = (u32)h[10] | ((u32)h[11] << 16);
  p1.z = (u32)h[12] | ((u32)h[13] << 16); p1.w = (u32)h[14] | ((u32)h[15] << 16);
  *(uint4*)&xb[(size_t)(bi + r) * P + cg] = p0;
  *(uint4*)&xb[(size_t)(bi + r) * P + cg + 8] = p1;
#pragma unroll
  for (int e = 0; e < 16; e++) tlT[cg + e][r] = h[e];
  __syncthreads();
  const int c = tid >> 1, hh = tid & 1;
  uint4 q0 = *(const uint4*)&tlT[c][hh * 16];
  uint4 q1 = *(const uint4*)&tlT[c][hh * 16 + 8];
  *(uint4*)&xbT[(size_t)c * N + bi + hh * 16] = q0;
  *(uint4*)&xbT[(size_t)c * N + bi + hh * 16 + 8] = q1;
}

// ---------- K1b: anchor lower bound on max d2 ----------
__global__ __launch_bounds__(128) void k_anchor(const u16* __restrict__ xb, const float* __restrict__ x2,
                                                u32* __restrict__ mdb) {
  const int i = blockIdx.x * 128 + threadIdx.x;
  const uint4* ra = (const uint4*)(xb + (size_t)i * P);
  const uint4* r0 = (const uint4*)xb;
  float dot = 0.0f;
#pragma unroll
  for (int q = 0; q < 16; ++q) {
    uint4 a = ra[q], b = r0[q];
    u32 aa[4] = {a.x, a.y, a.z, a.w}, bb[4] = {b.x, b.y, b.z, b.w};
#pragma unroll
    for (int e = 0; e < 4; e++) {
      dot = fmaf(b2f((u16)(aa[e] & 0xffffu)), b2f((u16)(bb[e] & 0xffffu)), dot);
      dot = fmaf(b2f((u16)(aa[e] >> 16)), b2f((u16)(bb[e] >> 16)), dot);
    }
  }
  float d2 = fmaxf(x2[i] + x2[0] - 2.0f * dot, 0.0f);
#pragma unroll
  for (int o = 32; o > 0; o >>= 1) d2 = fmaxf(d2, __shfl_down(d2, o));
  if ((threadIdx.x & 63) == 0) atomicMax(mdb, __float_as_uint(d2));
}

// ---------- K2: full max pairwise d2 — early-outs if anchor proves md >= max(r) ----------
__global__ __launch_bounds__(512, 4) void k_grammax(const u16* __restrict__ xb, const float* __restrict__ x2,
                                                    u32* __restrict__ mdb,
                                                    const float* __restrict__ r0p, const float* __restrict__ r1p,
                                                    const float* __restrict__ r2p) {
  const float rmax = fmaxf(r0p[0], fmaxf(r1p[0], r2p[0])) * 1.02f;
  if (__uint_as_float(*mdb) >= rmax * rmax) return;
  __shared__ uint4 LA[1024];
  const int j0 = blockIdx.x * 64;
  const int cid = blockIdx.y;
  if (cid * 512 + 512 <= j0) return;
  const int tid = threadIdx.x;
  const int lane = tid & 63, w = tid >> 6;
  const int lm = lane & 15, quad = lane >> 4;
  {
    const uint4* g = (const uint4*)(xb + (size_t)j0 * P);
#pragma unroll
    for (int it = 0; it < 2; ++it) {
      int c = it * 512 + tid;
      int row = c >> 4, ch = c & 15;
      LA[row * 16 + (ch ^ (row & 7))] = g[c];
    }
  }
  float x2j[4][4];
#pragma unroll
  for (int u = 0; u < 4; u++)
#pragma unroll
    for (int reg = 0; reg < 4; reg++) x2j[u][reg] = x2[j0 + u * 16 + quad * 4 + reg];
  __syncthreads();
  float lmax = 0.0f;
  for (int t = 0; t < ITILES; ++t) {
    const int i0 = cid * 512 + t * 128;
    if (i0 + 128 <= j0) continue;
    f32x4 accG[4];
#pragma unroll
    for (int u = 0; u < 4; u++) accG[u] = {0.f, 0.f, 0.f, 0.f};
    const u16* gb = xb + (size_t)(i0 + w * 16 + lm) * P;
#pragma unroll
    for (int ks = 0; ks < 4; ++ks) {
      s16x8 bf = *(const s16x8*)(gb + ks * 32 + quad * 8);
      s16x8 af[4];
#pragma unroll
      for (int u = 0; u < 4; u++) { int m = u * 16 + lm; af[u] = *(const s16x8*)&LA[m * 16 + ((ks * 4 + quad) ^ (m & 7))]; }
#pragma unroll
      for (int u = 0; u < 4; u++) accG[u] = MFMA(af[u], bf, accG[u]);
    }
    float x2i = x2[i0 + w * 16 + lm];
#pragma unroll
    for (int u = 0; u < 4; u++)
#pragma unroll
      for (int reg = 0; reg < 4; reg++) lmax = fmaxf(lmax, x2j[u][reg] + x2i - 2.0f * accG[u][reg]);
  }
#pragma unroll
  for (int o = 32; o > 0; o >>= 1) lmax = fmaxf(lmax, __shfl_down(lmax, o));
  if (lane == 0) atomicMax(mdb, __float_as_uint(lmax));
}

// ---------- K3: fused alpha (CHUNKS=8, register-prefetched xbT fragments) ----------
__global__ __launch_bounds__(512, 4) void k_alpha(const u16* __restrict__ xb, const u16* __restrict__ xbT,
                                                  const float* __restrict__ x2,
                                                  float* __restrict__ muP, float* __restrict__ S1P,
                                                  const float* __restrict__ r0p, const u32* __restrict__ mdb) {
  __shared__ uint4 LA[1024];     // xb_j 64x128 swizzled
  __shared__ u16 W16[64 * 136];  // W[j][i]
  __shared__ float S1L[64];
  const int j0 = blockIdx.x * 64, cid = blockIdx.y;
  const int tid = threadIdx.x;
  const int lane = tid & 63, w = tid >> 6;
  const int lm = lane & 15, quad = lane >> 4;
  {
    const uint4* g = (const uint4*)(xb + (size_t)j0 * P);
#pragma unroll
    for (int it = 0; it < 2; ++it) {
      int c = it * 512 + tid;
      int row = c >> 4, ch = c & 15;
      LA[row * 16 + (ch ^ (row & 7))] = g[c];
    }
  }
  if (tid < 64) S1L[tid] = 0.0f;
  const float mdf = sqrtf(fmaxf(__uint_as_float(*mdb), 1e-12f));
  const float re = fminf(r0p[0], mdf);
  const float re2 = re * re, inv_re2 = 1.0f / re2;
  float x2j[4];
#pragma unroll
  for (int v = 0; v < 4; v++) x2j[v] = x2[j0 + v * 16 + lm];
  f32x4 accPV[4];
#pragma unroll
  for (int u = 0; u < 4; u++) accPV[u] = {0.f, 0.f, 0.f, 0.f};
  float sjv[4] = {0.f, 0.f, 0.f, 0.f};
  __syncthreads();
  for (int t = 0; t < ITILES; ++t) {
    const int i0 = (cid * ITILES + t) * 128;
    f32x4 accG[4];
#pragma unroll
    for (int v = 0; v < 4; v++) accG[v] = {0.f, 0.f, 0.f, 0.f};
    const u16* ga = xb + (size_t)(i0 + w * 16 + lm) * P;
#pragma unroll
    for (int ks = 0; ks < 4; ++ks) {
      s16x8 af = *(const s16x8*)(ga + ks * 32 + quad * 8);
      s16x8 bf[4];
#pragma unroll
      for (int v = 0; v < 4; v++) { int m = v * 16 + lm; bf[v] = *(const s16x8*)&LA[m * 16 + ((ks * 4 + quad) ^ (m & 7))]; }
#pragma unroll
      for (int v = 0; v < 4; v++) accG[v] = MFMA(af, bf[v], accG[v]);
    }
    // prefetch PV-phase B fragments (independent of W) to hide latency behind epilogue+barriers
    const u16* gx = xbT + (size_t)(w * 16 + lm) * N + i0;
    s16x8 bx0 = *(const s16x8*)(gx + 0 * 32 + quad * 8);
    s16x8 bx1 = *(const s16x8*)(gx + 1 * 32 + quad * 8);
    s16x8 bx2 = *(const s16x8*)(gx + 2 * 32 + quad * 8);
    s16x8 bx3 = *(const s16x8*)(gx + 3 * 32 + quad * 8);
    float4 x2iv = *(const float4*)&x2[i0 + w * 16 + quad * 4];
    const float xi[4] = {x2iv.x, x2iv.y, x2iv.z, x2iv.w};
    u16 wv4[4][4];
#pragma unroll
    for (int v = 0; v < 4; v++)
#pragma unroll
      for (int reg = 0; reg < 4; reg++) {
        float d2 = fmaxf(xi[reg] + x2j[v] - 2.0f * accG[v][reg], 1e-12f);
        float wt = 0.0f;
        if (d2 < re2) { float b = 1.0f - d2 * inv_re2; wt = b * b * b; }
        sjv[v] += wt;
        wv4[v][reg] = f2b(wt);
      }
    __syncthreads();  // prev tile's W16 readers done
#pragma unroll
    for (int v = 0; v < 4; v++) {
      ushort4 pk; pk.x = wv4[v][0]; pk.y = wv4[v][1]; pk.z = wv4[v][2]; pk.w = wv4[v][3];
      *(ushort4*)&W16[(v * 16 + lm) * 136 + w * 16 + quad * 4] = pk;
    }
    __syncthreads();
    const s16x8 bxs[4] = {bx0, bx1, bx2, bx3};
#pragma unroll
    for (int ks = 0; ks < 4; ++ks) {
      s16x8 aw[4];
#pragma unroll
      for (int u = 0; u < 4; u++) { int m = u * 16 + lm; aw[u] = *(const s16x8*)&W16[m * 136 + ks * 32 + quad * 8]; }
#pragma unroll
      for (int u = 0; u < 4; u++) accPV[u] = MFMA(aw[u], bxs[ks], accPV[u]);
    }
  }
  float* mu = muP + (size_t)cid * N * P;
#pragma unroll
  for (int u = 0; u < 4; u++)
#pragma unroll
    for (int reg = 0; reg < 4; reg++)
      __builtin_nontemporal_store(accPV[u][reg],
        &mu[(size_t)(j0 + u * 16 + quad * 4 + reg) * P + w * 16 + lm]);
#pragma unroll
  for (int v = 0; v < 4; v++) atomicAdd(&S1L[v * 16 + lm], sjv[v]);
  __syncthreads();
  if (tid < 64) S1P[cid * N + j0 + tid] = S1L[tid];
}

// ---------- K4: U finalize, Ub=bf16(U), u2,cj from bf16 ----------
__global__ __launch_bounds__(128) void k_finU(const float* __restrict__ x, const u16* __restrict__ xb,
                                              const float* __restrict__ muP, const float* __restrict__ S1P,
                                              u16* __restrict__ Ub, float* __restrict__ u2, float* __restrict__ cj) {
  const int j = blockIdx.x, t = threadIdx.x;
  float ssum = 0.0f, msum = 0.0f;
#pragma unroll
  for (int c = 0; c < CHUNKS; ++c) {
    ssum += S1P[c * N + j];
    msum += __builtin_nontemporal_load(&muP[((size_t)c * N + j) * P + t]);
  }
  float xv = x[(size_t)j * P + t];
  float uval = 0.0f;
  if (ssum > 0.0f) uval = xv - msum / ssum;
  u16 ub = f2b(uval);
  Ub[(size_t)j * P + t] = ub;
  float uf = b2f(ub);
  float xbf = b2f(xb[(size_t)j * P + t]);
  float a = uf * uf, b = xbf * uf;
#pragma unroll
  for (int o = 32; o > 0; o >>= 1) { a += __shfl_down(a, o); b += __shfl_down(b, o); }
  __shared__ float ra[2], rb[2];
  if ((t & 63) == 0) { ra[t >> 6] = a; rb[t >> 6] = b; }
  __syncthreads();
  if (t == 0) { u2[j] = ra[0] + ra[1]; cj[j] = rb[0] + rb[1]; }
}

// ---------- K5: fused beta (CHUNKS=8; square-space w2; nt stores; prefetched xbT fragments) ----------
__global__ __launch_bounds__(512, 4) void k_betaez(const u16* __restrict__ xb, const u16* __restrict__ Ub,
                                                   const u16* __restrict__ xbT,
                                                   const float* __restrict__ x2, const float* __restrict__ u2,
                                                   const float* __restrict__ cj,
                                                   float* __restrict__ ezP, float* __restrict__ S2P,
                                                   const float* __restrict__ r1p, const float* __restrict__ r2p,
                                                   const u32* __restrict__ mdb) {
  __shared__ uint4 LA[1024];
  __shared__ uint4 LU[1024];
  __shared__ u16 W16[64 * 136];
  __shared__ float S2L[64];
  const int j0 = blockIdx.x * 64, cid = blockIdx.y;
  const int tid = threadIdx.x;
  const int lane = tid & 63, w = tid >> 6;
  const int lm = lane & 15, quad = lane >> 4;
  {
    const uint4* ga = (const uint4*)(xb + (size_t)j0 * P);
    const uint4* gu = (const uint4*)(Ub + (size_t)j0 * P);
#pragma unroll
    for (int it = 0; it < 2; ++it) {
      int c = it * 512 + tid;
      int row = c >> 4, ch = c & 15;
      int sw = row * 16 + (ch ^ (row & 7));
      LA[sw] = ga[c];
      LU[sw] = gu[c];
    }
  }
  if (tid < 64) S2L[tid] = 0.0f;
  const float mdf = sqrtf(fmaxf(__uint_as_float(*mdb), 1e-12f));
  const float r1e = fminf(r1p[0], mdf), r2e = fminf(r2p[0], mdf);
  const float r1q = r1e * r1e, r1h = 0.25f * r1q;
  const float r2q = r2e * r2e, r2h = 0.25f * r2q;
  const float inv_r1 = 1.0f / r1e, inv_r2 = 1.0f / r2e;
  float x2j[4], u2j[4], ncj[4];
#pragma unroll
  for (int v = 0; v < 4; v++) {
    int jj = j0 + v * 16 + lm;
    x2j[v] = x2[jj]; u2j[v] = u2[jj]; ncj[v] = -cj[jj];
  }
  f32x4 accPV[4];
#pragma unroll
  for (int u = 0; u < 4; u++) accPV[u] = {0.f, 0.f, 0.f, 0.f};
  float sjv[4] = {0.f, 0.f, 0.f, 0.f};
  __syncthreads();
  for (int t = 0; t < ITILES; ++t) {
    const int i0 = (cid * ITILES + t) * 128;
    f32x4 accG[4], accP[4];
#pragma unroll
    for (int v = 0; v < 4; v++) {
      accG[v] = {0.f, 0.f, 0.f, 0.f};
      accP[v] = {ncj[v], ncj[v], ncj[v], ncj[v]};  // ps = x_i.U_j - cj_j via C-init
    }
    const u16* ga = xb + (size_t)(i0 + w * 16 + lm) * P;
#pragma unroll
    for (int ks = 0; ks < 4; ++ks) {
      s16x8 af = *(const s16x8*)(ga + ks * 32 + quad * 8);
      s16x8 bf[4], bu[4];
#pragma unroll
      for (int v = 0; v < 4; v++) {
        int m = v * 16 + lm;
        int off = m * 16 + ((ks * 4 + quad) ^ (m & 7));
        bf[v] = *(const s16x8*)&LA[off];
        bu[v] = *(const s16x8*)&LU[off];
      }
#pragma unroll
      for (int v = 0; v < 4; v++) {
        accG[v] = MFMA(af, bf[v], accG[v]);
        accP[v] = MFMA(af, bu[v], accP[v]);
      }
    }
    // prefetch PV-phase B fragments (independent of W)
    const u16* gx = xbT + (size_t)(w * 16 + lm) * N + i0;
    s16x8 bx0 = *(const s16x8*)(gx + 0 * 32 + quad * 8);
    s16x8 bx1 = *(const s16x8*)(gx + 1 * 32 + quad * 8);
    s16x8 bx2 = *(const s16x8*)(gx + 2 * 32 + quad * 8);
    s16x8 bx3 = *(const s16x8*)(gx + 3 * 32 + quad * 8);
    float4 x2iv = *(const float4*)&x2[i0 + w * 16 + quad * 4];
    const float xi[4] = {x2iv.x, x2iv.y, x2iv.z, x2iv.w};
    u16 wv4[4][4];
#pragma unroll
    for (int v = 0; v < 4; v++)
#pragma unroll
      for (int reg = 0; reg < 4; reg++) {
        float d2 = fmaxf(xi[reg] + x2j[v] - 2.0f * accG[v][reg], 1e-12f);
        float ps = accP[v][reg];
        float du2 = fmaxf(ps * ps * u2j[v], 1e-6f);
        float dv2 = fmaxf(d2 - du2, 1e-6f);
        float wt;
        if (dv2 >= r1q || du2 >= r2q) {
          wt = 0.0f;
        } else if (dv2 < r1h && du2 < r2h) {
          wt = 1.0f;
        } else {
          float wa = 1.0f;
          if (dv2 >= r1h) { float dv = sqrtf(dv2); float tt = 2.0f * dv * inv_r1 - 1.0f; float b = 1.0f - tt * tt; wa = b * b * b; }
          float wb = 1.0f;
          if (du2 >= r2h) { float du = sqrtf(du2); float tt = 2.0f * du * inv_r2 - 1.0f; float b = 1.0f - tt * tt; wb = b * b * b; }
          wt = wa * wb;
        }
        sjv[v] += wt;
        wv4[v][reg] = f2b(wt);
      }
    __syncthreads();
#pragma unroll
    for (int v = 0; v < 4; v++) {
      ushort4 pk; pk.x = wv4[v][0]; pk.y = wv4[v][1]; pk.z = wv4[v][2]; pk.w = wv4[v][3];
      *(ushort4*)&W16[(v * 16 + lm) * 136 + w * 16 + quad * 4] = pk;
    }
    __syncthreads();
    const s16x8 bxs[4] = {bx0, bx1, bx2, bx3};
#pragma unroll
    for (int ks = 0; ks < 4; ++ks) {
      s16x8 aw[4];
#pragma unroll
      for (int u = 0; u < 4; u++) { int m = u * 16 + lm; aw[u] = *(const s16x8*)&W16[m * 136 + ks * 32 + quad * 8]; }
#pragma unroll
      for (int u = 0; u < 4; u++) accPV[u] = MFMA(aw[u], bxs[ks], accPV[u]);
    }
  }
  float* ez = ezP + (size_t)cid * N * P;
#pragma unroll
  for (int u = 0; u < 4; u++)
#pragma unroll
    for (int reg = 0; reg < 4; reg++)
      __builtin_nontemporal_store(accPV[u][reg],
        &ez[(size_t)(j0 + u * 16 + quad * 4 + reg) * P + w * 16 + lm]);
#pragma unroll
  for (int v = 0; v < 4; v++) atomicAdd(&S2L[v * 16 + lm], sjv[v]);
  __syncthreads();
  if (tid < 64) S2P[cid * N + j0 + tid] = S2L[tid];
}

// ---------- K6: e_Z reduce+normalize + autoencoder + MSE ----------
#define AE_ROWS 16
__global__ __launch_bounds__(256) void k_ae(const float* __restrict__ x, const float* __restrict__ ezP,
                                            const float* __restrict__ S2P,
                                            const float* __restrict__ We1, const float* __restrict__ be1,
                                            const float* __restrict__ We2, const float* __restrict__ be2,
                                            const float* __restrict__ Wd1, const float* __restrict__ bd1,
                                            const float* __restrict__ Wd2, const float* __restrict__ bd2,
                                            float* __restrict__ out) {
  __shared__ float We1T[P][33];
  __shared__ float We2T[LDIM][33];
  __shared__ float Wd1T[LDIM][33];
  __shared__ float Wd2T[LDIM][129];
  __shared__ float ezs[AE_ROWS][P];
  __shared__ float h1s[AE_ROWS][LDIM], zbs[AE_ROWS][LDIM], h2s[AE_ROWS][LDIM];
  __shared__ float be1s[LDIM], be2s[LDIM], bd1s[LDIM], bd2s[P];
  __shared__ float s2s[AE_ROWS];
  const int tid = threadIdx.x;
  const int r0 = blockIdx.x * AE_ROWS;
  for (int idx = tid; idx < P * LDIM; idx += 256) {
    int o = idx >> 7, k = idx & 127;
    We1T[k][o] = We1[idx];
    int o2 = idx >> 5, k2 = idx & 31;
    Wd2T[k2][o2] = Wd2[idx];
  }
  for (int idx = tid; idx < LDIM * LDIM; idx += 256) {
    int o = idx >> 5, k = idx & 31;
    We2T[k][o] = We2[idx];
    Wd1T[k][o] = Wd1[idx];
  }
  if (tid < LDIM) { be1s[tid] = be1[tid]; be2s[tid] = be2[tid]; bd1s[tid] = bd1[tid]; }
  if (tid < P) bd2s[tid] = bd2[tid];
  if (tid >= 128 && tid < 128 + AE_ROWS) {
    int r = tid - 128;
    float s = 0.0f;
#pragma unroll
    for (int c = 0; c < CHUNKS; ++c) s += S2P[c * N + r0 + r];
    s2s[r] = s;
  }
  __syncthreads();
  for (int idx = tid; idx < AE_ROWS * P; idx += 256) {
    int r = idx >> 7, col = idx & 127;
    int row = r0 + r;
    float es = 0.0f;
#pragma unroll
    for (int c = 0; c < CHUNKS; ++c) es += __builtin_nontemporal_load(&ezP[((size_t)c * N + row) * P + col]);
    float xv = x[(size_t)row * P + col];
    ezs[r][col] = (s2s[r] > 0.0f) ? (es / s2s[r]) : xv;
  }
  __syncthreads();
  {
    const int o = tid & 31, rh = tid >> 5;
#pragma unroll
    for (int rr = 0; rr < 2; rr++) {
      int r = rh + rr * 8;
      float a = be1s[o];
#pragma unroll 8
      for (int k = 0; k < P; k++) a = fmaf(We1T[k][o], ezs[r][k], a);
      h1s[r][o] = geluf(a);
    }
  }
  __syncthreads();
  {
    const int o = tid & 31, rh = tid >> 5;
#pragma unroll
    for (int rr = 0; rr < 2; rr++) {
      int r = rh + rr * 8;
      float a = be2s[o];
#pragma unroll
      for (int k = 0; k < LDIM; k++) a = fmaf(We2T[k][o], h1s[r][k], a);
      zbs[r][o] = a;
    }
  }
  __syncthreads();
  {
    const int o = tid & 31, rh = tid >> 5;
#pragma unroll
    for (int rr = 0; rr < 2; rr++) {
      int r = rh + rr * 8;
      float a = bd1s[o];
#pragma unroll
      for (int k = 0; k < LDIM; k++) a = fmaf(Wd1T[k][o], zbs[r][k], a);
      h2s[r][o] = geluf(a);
    }
  }
  __syncthreads();
  {
    const int o = tid & 127, rh = tid >> 7;
    float part = 0.0f;
#pragma unroll
    for (int rr = 0; rr < 8; rr++) {
      int r = rh + rr * 2;
      int row = r0 + r;
      float a = bd2s[o];
#pragma unroll
      for (int k = 0; k < LDIM; k++) a = fmaf(Wd2T[k][o], h2s[r][k], a);
      float xh = 1.0f / (1.0f + expf(-a));
      float diff = x[(size_t)row * P + o] - xh;
      part = fmaf(diff, diff, part);
    }
#pragma unroll
    for (int off = 32; off > 0; off >>= 1) part += __shfl_down(part, off);
    if ((tid & 63) == 0) atomicAdd(out, part * (1.0f / ((float)N * (float)P)));
  }
}

extern "C" void kernel_launch(void* const* d_in, const int* in_sizes, int n_in,
                              void* d_out, int out_size, void* d_ws, size_t ws_size,
                              hipStream_t stream) {
  const float* x   = (const float*)d_in[0];
  const float* r0  = (const float*)d_in[1];
  const float* r1  = (const float*)d_in[2];
  const float* r2  = (const float*)d_in[3];
  const float* We1 = (const float*)d_in[4];
  const float* be1 = (const float*)d_in[5];
  const float* We2 = (const float*)d_in[6];
  const float* be2 = (const float*)d_in[7];
  const float* Wd1 = (const float*)d_in[8];
  const float* bd1 = (const float*)d_in[9];
  const float* Wd2 = (const float*)d_in[10];
  const float* bd2 = (const float*)d_in[11];
  float* out = (float*)d_out;

  char* base = (char*)d_ws;
  size_t off = 0;
  u16* xb  = (u16*)(base + off); off += (size_t)N * P * 2;
  u16* xbT = (u16*)(base + off); off += (size_t)N * P * 2;
  u16* Ub  = (u16*)(base + off); off += (size_t)N * P * 2;
  float* muP = (float*)(base + off); off += (size_t)CHUNKS * N * P * 4;  // 16MB
  float* ezP = (float*)(base + off); off += (size_t)CHUNKS * N * P * 4;  // 16MB
  float* S1P = (float*)(base + off); off += (size_t)CHUNKS * N * 4;
  float* S2P = (float*)(base + off); off += (size_t)CHUNKS * N * 4;
  float* x2  = (float*)(base + off); off += (size_t)N * 4;
  u32* mdb   = (u32*)(base + off); off += 4;
  float* u2  = (float*)(base + off); off += (size_t)N * 4;
  float* cjv = (float*)(base + off); off += (size_t)N * 4;

  hipLaunchKernelGGL(k_prep, dim3(N / 32), dim3(256), 0, stream, x, xb, xbT, x2, mdb, out);
  hipLaunchKernelGGL(k_anchor, dim3(N / 128), dim3(128), 0, stream, xb, x2, mdb);
  hipLaunchKernelGGL(k_grammax, dim3(N / 64, CHUNKS), dim3(512), 0, stream, xb, x2, mdb, r0, r1, r2);
  hipLaunchKernelGGL(k_alpha, dim3(N / 64, CHUNKS), dim3(512), 0, stream, xb, xbT, x2, muP, S1P, r0, mdb);
  hipLaunchKernelGGL(k_finU, dim3(N), dim3(128), 0, stream, x, xb, muP, S1P, Ub, u2, cjv);
  hipLaunchKernelGGL(k_betaez, dim3(N / 64, CHUNKS), dim3(512), 0, stream, xb, Ub, xbT, x2, u2, cjv, ezP, S2P, r1, r2, mdb);
  hipLaunchKernelGGL(k_ae, dim3(N / AE_ROWS), dim3(256), 0, stream, x, ezP, S2P, We1, be1, We2, be2, Wd1, bd1, Wd2, bd2, out);
}